// Round 6
// baseline (545.941 us; speedup 1.0000x reference)
//
#include <hip/hip_runtime.h>
#include <cstdint>

// ---------- problem constants ----------
#define B_   2
#define S_   4096
#define D_   768
#define H_   12
#define DH_  64
#define BH_  (B_*H_)       // 24
#define M_   (B_*S_)       // 8192
#define SCALE 0.125f       // 1/sqrt(64)

typedef _Float16 fp16;
typedef __attribute__((ext_vector_type(8))) _Float16 fp16x8;
typedef __attribute__((ext_vector_type(4))) _Float16 fp16x4;
typedef __attribute__((ext_vector_type(4))) float    f32x4;

#define MFMA16(a,b,c) __builtin_amdgcn_mfma_f32_16x16x32_f16((a),(b),(c),0,0,0)

__device__ __forceinline__ float exp2_hw(float x) {
  float r; asm("v_exp_f32 %0, %1" : "=v"(r) : "v"(x)); return r;
}

// ---------- async global->LDS, 16B ----------
__device__ __forceinline__ void gld_lds16(const void* g, void* l) {
  __builtin_amdgcn_global_load_lds(
      (const __attribute__((address_space(1))) unsigned int*)g,
      (__attribute__((address_space(3))) unsigned int*)l, 16, 0, 0);
}

// Stage a 64-row x 128-byte tile into LDS. Linear LDS dest (required by
// global_load_lds), inverse-swizzled GLOBAL source, swizzled reads.
__device__ __forceinline__ void stage64x128(const char* gbase, int pitch,
                                            char* lds, int tid) {
  const int lane = tid & 63, wv = tid >> 6;
#pragma unroll
  for (int j = 0; j < 2; ++j) {
    const int o   = (wv*2 + j)*1024 + lane*16;
    const int row = o >> 7;
    const int cb  = (o & 127) ^ ((row & 7) << 4);
    gld_lds16(gbase + (size_t)row*pitch + cb, lds + (wv*2 + j)*1024);
  }
}

// ---------- kernel 1: W transpose + hi/lo split ----------
__global__ __launch_bounds__(256) void prep_w(const float* __restrict__ wq,
                                              const float* __restrict__ wk,
                                              const float* __restrict__ wv,
                                              fp16* __restrict__ wt) {
  const int idx = blockIdx.x*256 + threadIdx.x;       // 3*768*768 total
  const int mat = idx / (768*768);
  const int e   = idx % (768*768);
  const int n   = e / 768, k = e % 768;
  const float* w = mat == 0 ? wq : (mat == 1 ? wk : wv);
  const float v = w[(size_t)k*768 + n];
  fp16* base = wt + (size_t)mat * (2*768*768);
  const fp16 hv = (fp16)v;
  base[e]            = hv;
  base[768*768 + e]  = (fp16)(v - (float)hv);
}

// ---------- kernel 1b: X hi/lo split (vectorized, memory-bound) ----------
__global__ __launch_bounds__(256) void prep_x(const float* __restrict__ x,
                                              fp16* __restrict__ xh,
                                              fp16* __restrict__ xl) {
  const size_t i = ((size_t)blockIdx.x*256 + threadIdx.x) * 8;
  const f32x4 a = *(const f32x4*)(x + i);
  const f32x4 b = *(const f32x4*)(x + i + 4);
  fp16x8 hv, lv;
#pragma unroll
  for (int j = 0; j < 8; ++j) {
    const float v = j < 4 ? a[j] : b[j - 4];
    const fp16 h = (fp16)v;
    hv[j] = h; lv[j] = (fp16)(v - (float)h);
  }
  *(fp16x8*)(xh + i) = hv;
  *(fp16x8*)(xl + i) = lv;
}

// ---------- kernel 2A: projection GEMM, staged-A (f16x3), 64x64 tile ----------
__global__ __launch_bounds__(256) void proj_gemmA(
    const fp16* __restrict__ xh, const fp16* __restrict__ xl,
    const fp16* __restrict__ wth,
    fp16* __restrict__ ph, fp16* __restrict__ pl,
    fp16* __restrict__ vtp, int isV) {
  __shared__ __align__(16) char sm[32768];
  char* sXh = sm;
  char* sXl = sm + 8192;
  char* sWh = sm + 16384;
  char* sWl = sm + 24576;
  const fp16* wtl = wth + 768*768;
  const int tid = threadIdx.x, lane = tid & 63, wv = tid >> 6;
  const int c = lane & 15, g = lane >> 4;
  const int r128 = c * 128;
  const int co0 = ((c & 7) ^ g) << 4;
  const int co1 = co0 ^ 64;
  const int mb  = blockIdx.x * 64;
  const int h   = blockIdx.y;
  const int nb  = h * 64;

  f32x4 acc[4] = {};
  for (int k0 = 0; k0 < 768; k0 += 64) {
    __syncthreads();
    stage64x128((const char*)(xh  + (size_t)mb*768 + k0), 1536, sXh, tid);
    stage64x128((const char*)(xl  + (size_t)mb*768 + k0), 1536, sXl, tid);
    stage64x128((const char*)(wth + (size_t)nb*768 + k0), 1536, sWh, tid);
    stage64x128((const char*)(wtl + (size_t)nb*768 + k0), 1536, sWl, tid);
    __syncthreads();

    const int arow = (wv*16 + c) * 128;
    const fp16x8 ah0 = *(const fp16x8*)(sXh + arow + co0);
    const fp16x8 ah1 = *(const fp16x8*)(sXh + arow + co1);
    const fp16x8 al0 = *(const fp16x8*)(sXl + arow + co0);
    const fp16x8 al1 = *(const fp16x8*)(sXl + arow + co1);
#pragma unroll
    for (int nt = 0; nt < 4; ++nt) {
      const char* wb  = sWh + r128 + nt*2048;
      const char* wlb = sWl + r128 + nt*2048;
      const fp16x8 bh0 = *(const fp16x8*)(wb  + co0);
      const fp16x8 bh1 = *(const fp16x8*)(wb  + co1);
      const fp16x8 bl0 = *(const fp16x8*)(wlb + co0);
      const fp16x8 bl1 = *(const fp16x8*)(wlb + co1);
      acc[nt] = MFMA16(ah0, bh0, acc[nt]);
      acc[nt] = MFMA16(ah0, bl0, acc[nt]);
      acc[nt] = MFMA16(al0, bh0, acc[nt]);
      acc[nt] = MFMA16(ah1, bh1, acc[nt]);
      acc[nt] = MFMA16(ah1, bl1, acc[nt]);
      acc[nt] = MFMA16(al1, bh1, acc[nt]);
    }
  }

  if (!isV) {
#pragma unroll
    for (int nt = 0; nt < 4; ++nt)
#pragma unroll
      for (int r = 0; r < 4; ++r) {
        const int m = mb + wv*16 + g*4 + r;      // C/D row = 4*(l>>4)+reg
        const int bb = m >> 12, s = m & (S_-1);
        const size_t idx = ((size_t)(bb*H_ + h)*S_ + s)*DH_ + nt*16 + c;
        const float v = acc[nt][r];
        const fp16 hv = (fp16)v;
        ph[idx] = hv;
        pl[idx] = (fp16)(v - (float)hv);
      }
  } else {
    __syncthreads();
    fp16* tile = (fp16*)sm;   // [64 d][64 m_local]
#pragma unroll
    for (int nt = 0; nt < 4; ++nt) {
      const int dd = nt*16 + c, ml = wv*16 + g*4;
      const fp16x4 hv = {(fp16)acc[nt][0], (fp16)acc[nt][1],
                         (fp16)acc[nt][2], (fp16)acc[nt][3]};
      *(fp16x4*)(tile + dd*64 + ml) = hv;
    }
    __syncthreads();
    const int bb = mb >> 12, s0 = mb & (S_-1);
    const int dd = tid >> 2, ml0 = (tid & 3) * 16;
    const size_t obase = ((size_t)(bb*H_ + h)*DH_ + dd)*S_ + s0 + ml0;
#pragma unroll
    for (int u = 0; u < 2; ++u)
      *(fp16x8*)(vtp + obase + u*8) = *(const fp16x8*)(tile + dd*64 + ml0 + u*8);
  }
}

// ---------- kernel 2B: fallback proj (inline split), used if ws too small ----
__global__ __launch_bounds__(256) void proj_gemm(
    const float* __restrict__ xq, const float* __restrict__ xk,
    const float* __restrict__ xv, const fp16* __restrict__ wt,
    fp16* __restrict__ qhi, fp16* __restrict__ qlo,
    fp16* __restrict__ khi, fp16* __restrict__ klo,
    fp16* __restrict__ vtp) {
  __shared__ __align__(16) char sm[16384];
  char* sWh = sm;
  char* sWl = sm + 8192;
  const int tid = threadIdx.x, lane = tid & 63, wv = tid >> 6;
  const int c = lane & 15, g = lane >> 4;
  const int r128 = c * 128;
  const int co0 = ((c & 7) ^ g) << 4;
  const int co1 = co0 ^ 64;
  const int mb  = blockIdx.x * 64;
  const int h   = blockIdx.y;
  const int nb  = h * 64;
  const int mat = blockIdx.z;
  const float* x = mat == 0 ? xq : (mat == 1 ? xk : xv);
  const fp16* wth = wt + (size_t)mat * (2*768*768);
  const fp16* wtl = wth + 768*768;

  f32x4 acc[4] = {};
  const int xrow = mb + wv*16 + c;

  for (int k0 = 0; k0 < 768; k0 += 64) {
    __syncthreads();
    stage64x128((const char*)(wth + (size_t)nb*768 + k0), 1536, sWh, tid);
    stage64x128((const char*)(wtl + (size_t)nb*768 + k0), 1536, sWl, tid);
    __syncthreads();

    fp16x8 ah[2], al[2];
#pragma unroll
    for (int ks = 0; ks < 2; ++ks) {
      const float* xp = x + (size_t)xrow*768 + k0 + ks*32 + g*8;
      const f32x4 x0 = *(const f32x4*)xp;
      const f32x4 x1 = *(const f32x4*)(xp + 4);
#pragma unroll
      for (int j = 0; j < 8; ++j) {
        const float v = j < 4 ? x0[j] : x1[j - 4];
        const fp16 hv = (fp16)v;
        ah[ks][j] = hv;
        al[ks][j] = (fp16)(v - (float)hv);
      }
    }
#pragma unroll
    for (int ks = 0; ks < 2; ++ks)
#pragma unroll
      for (int nt = 0; nt < 4; ++nt) {
        const char* wb  = sWh + r128 + nt*2048;
        const char* wlb = sWl + r128 + nt*2048;
        const int co = ks ? co1 : co0;
        const fp16x8 bh = *(const fp16x8*)(wb  + co);
        const fp16x8 bl = *(const fp16x8*)(wlb + co);
        acc[nt] = MFMA16(ah[ks], bh, acc[nt]);
        acc[nt] = MFMA16(ah[ks], bl, acc[nt]);
        acc[nt] = MFMA16(al[ks], bh, acc[nt]);
      }
  }

  if (mat < 2) {
    fp16* ph = mat ? khi : qhi;
    fp16* pl = mat ? klo : qlo;
#pragma unroll
    for (int nt = 0; nt < 4; ++nt)
#pragma unroll
      for (int r = 0; r < 4; ++r) {
        const int m = mb + wv*16 + g*4 + r;
        const int bb = m >> 12, s = m & (S_-1);
        const size_t idx = ((size_t)(bb*H_ + h)*S_ + s)*DH_ + nt*16 + c;
        const float v = acc[nt][r];
        const fp16 hv = (fp16)v;
        ph[idx] = hv;
        pl[idx] = (fp16)(v - (float)hv);
      }
  } else {
    __syncthreads();
    fp16* tile = (fp16*)sm;
#pragma unroll
    for (int nt = 0; nt < 4; ++nt) {
      const int dd = nt*16 + c, ml = wv*16 + g*4;
      const fp16x4 hv = {(fp16)acc[nt][0], (fp16)acc[nt][1],
                         (fp16)acc[nt][2], (fp16)acc[nt][3]};
      *(fp16x4*)(tile + dd*64 + ml) = hv;
    }
    __syncthreads();
    const int bb = mb >> 12, s0 = mb & (S_-1);
    const int dd = tid >> 2, ml0 = (tid & 3) * 16;
    const size_t obase = ((size_t)(bb*H_ + h)*DH_ + dd)*S_ + s0 + ml0;
#pragma unroll
    for (int u = 0; u < 2; ++u)
      *(fp16x8*)(vtp + obase + u*8) = *(const fp16x8*)(tile + dd*64 + ml0 + u*8);
  }
}

// ---------- kernel 3: flash attention (LDS overlay: 32 KB -> 5 WG/CU) -------
// WG = one (b,h) x 64 q-rows; 4 waves x 16-q strips; kt loop over 64-kv tiles.
// Swapped QK^T: D[kv][q] = mfma(A=K_frag, B=Qt_frag) -> lane column = one q.
// Q staged through the K buffers (dead after fragment extraction).
__global__ __launch_bounds__(256) void mha_flash(
    const fp16* __restrict__ qhi, const fp16* __restrict__ qlo,
    const fp16* __restrict__ khi, const fp16* __restrict__ klo,
    const fp16* __restrict__ vt, float* __restrict__ out) {
  __shared__ __align__(16) char sm[32768];
  char* sKh = sm;             // 8KB each
  char* sKl = sm + 8192;
  char* sV  = sm + 16384;
  char* sP  = sm + 24576;     // 4 waves x 2KB

  const int tid = threadIdx.x, lane = tid & 63, wv = tid >> 6;
  const int c = lane & 15, g = lane >> 4;
  const int r128 = c * 128;
  const int co0 = ((c & 7) ^ g) << 4;      // == (g*16)^((c&7)<<4)
  const int co1 = co0 ^ 64;                // == (64+g*16)^((c&7)<<4)
  const int pg3 = (g & 1) << 3;
  const int pse = ((c & 7) ^ (g >> 1)) << 4;
  const int qb = blockIdx.x * 64;
  const int bh = blockIdx.y;
  const int b = bh / H_, h = bh % H_;

  // ---- prologue: Q through K buffers, extract fragments, then reuse LDS ----
  const size_t qoff = ((size_t)bh*S_ + qb) * DH_;
  stage64x128((const char*)(qhi + qoff), 128, sKh, tid);
  stage64x128((const char*)(qlo + qoff), 128, sKl, tid);
  __syncthreads();

  fp16x8 qfh[2], qfl[2];
  {
    const int qrow = (wv*16 + c) * 128;
    qfh[0] = *(const fp16x8*)(sKh + qrow + co0);
    qfh[1] = *(const fp16x8*)(sKh + qrow + co1);
    qfl[0] = *(const fp16x8*)(sKl + qrow + co0);
    qfl[1] = *(const fp16x8*)(sKl + qrow + co1);
  }

  float m_run = -1e30f, l_run = 0.f;
  f32x4 accO[4] = {};
  const float C2 = 0.125f * 1.4426950408889634f;   // SCALE * log2(e)

  for (int kt = 0; kt < S_/64; ++kt) {
    __syncthreads();   // prior-iter reads (and Q-frag reads at kt=0) complete
    const size_t koff = ((size_t)bh*S_ + kt*64) * DH_;
    stage64x128((const char*)(khi + koff), 128, sKh, tid);
    stage64x128((const char*)(klo + koff), 128, sKl, tid);
    stage64x128((const char*)(vt + (size_t)bh*DH_*S_ + kt*64), S_*2, sV, tid);
    __syncthreads();   // vmcnt(0) drain -> tiles resident

    // QK^T, f16x3
    f32x4 accS[4] = {};
#pragma unroll
    for (int t = 0; t < 4; ++t) {
      const char* kb = sKh + r128 + t*2048;
      const char* lb = sKl + r128 + t*2048;
      const fp16x8 kh0 = *(const fp16x8*)(kb + co0);
      const fp16x8 kh1 = *(const fp16x8*)(kb + co1);
      const fp16x8 kl0 = *(const fp16x8*)(lb + co0);
      const fp16x8 kl1 = *(const fp16x8*)(lb + co1);
      accS[t] = MFMA16(kh0, qfh[0], accS[t]);
      accS[t] = MFMA16(kh0, qfl[0], accS[t]);
      accS[t] = MFMA16(kl0, qfh[0], accS[t]);
      accS[t] = MFMA16(kh1, qfh[1], accS[t]);
      accS[t] = MFMA16(kh1, qfl[1], accS[t]);
      accS[t] = MFMA16(kl1, qfh[1], accS[t]);
    }

    // online softmax over kv (lane holds 16 of 64 scores for q=c)
    float mx = -1e30f;
#pragma unroll
    for (int t = 0; t < 4; ++t)
      mx = fmaxf(mx, fmaxf(fmaxf(accS[t][0], accS[t][1]),
                           fmaxf(accS[t][2], accS[t][3])));
    mx = fmaxf(mx, __shfl_xor(mx, 16));
    mx = fmaxf(mx, __shfl_xor(mx, 32));
    const float m_new = fmaxf(m_run, mx);
    const float nm = m_new * C2;
    const float corr = exp2_hw(__builtin_fmaf(m_run, C2, -nm));
    float psum = 0.f;
#pragma unroll
    for (int t = 0; t < 4; ++t)
#pragma unroll
      for (int r = 0; r < 4; ++r) {
        const float p = exp2_hw(__builtin_fmaf(accS[t][r], C2, -nm));
        accS[t][r] = p;
        psum += p;
      }
    psum += __shfl_xor(psum, 16);
    psum += __shfl_xor(psum, 32);
    l_run = l_run * corr + psum;
    m_run = m_new;

    // P -> per-wave LDS strip [16 q][64 kv] f16 (swizzled)
    char* pbase = sP + wv*2048 + r128;
#pragma unroll
    for (int t = 0; t < 4; ++t) {
      const fp16x4 pw = {(fp16)accS[t][0], (fp16)accS[t][1],
                         (fp16)accS[t][2], (fp16)accS[t][3]};
      *(fp16x4*)(pbase + (pg3 | (pse ^ (t*32)))) = pw;
    }

    // rescale O (corr is per q=c; accO rows are q'=4g+r -> shuffle)
    float cr[4];
#pragma unroll
    for (int r = 0; r < 4; ++r)
      cr[r] = __shfl(corr, (lane & 48) | (g*4 + r));
#pragma unroll
    for (int d = 0; d < 4; ++d)
#pragma unroll
      for (int r = 0; r < 4; ++r) accO[d][r] *= cr[r];

    // PV: A = P (rows q), B = V^T tile (k-contiguous)
    const fp16x8 pf0 = *(const fp16x8*)(pbase + co0);
    const fp16x8 pf1 = *(const fp16x8*)(pbase + co1);
#pragma unroll
    for (int d = 0; d < 4; ++d) {
      const char* vb = sV + r128 + d*2048;
      accO[d] = MFMA16(pf0, *(const fp16x8*)(vb + co0), accO[d]);
      accO[d] = MFMA16(pf1, *(const fp16x8*)(vb + co1), accO[d]);
    }
  }

  float inv[4];
#pragma unroll
  for (int r = 0; r < 4; ++r)
    inv[r] = 1.f / __shfl(l_run, (lane & 48) | (g*4 + r));
  const int s0 = qb + wv*16 + g*4;
#pragma unroll
  for (int d = 0; d < 4; ++d)
#pragma unroll
    for (int r = 0; r < 4; ++r)
      out[((size_t)(b*S_ + s0 + r))*D_ + h*DH_ + d*16 + c] = accO[d][r] * inv[r];
}

// ---------- launch ----------
extern "C" void kernel_launch(void* const* d_in, const int* in_sizes, int n_in,
                              void* d_out, int out_size, void* d_ws, size_t ws_size,
                              hipStream_t stream) {
  const float* xq = (const float*)d_in[0];
  const float* xk = (const float*)d_in[1];
  const float* xv = (const float*)d_in[2];
  const float* wq = (const float*)d_in[3];
  const float* wk = (const float*)d_in[4];
  const float* wv = (const float*)d_in[5];
  float* out = (float*)d_out;

  // ws layout (f16): Wt (6x768x768) | Qhi Qlo Khi Klo Vt | Xhi Xlo (optional)
  fp16* wt  = (fp16*)d_ws;
  fp16* qhi = wt + (size_t)6*768*768;
  const size_t PL = (size_t)BH_*S_*DH_;
  fp16* qlo = qhi + PL;
  fp16* khi = qlo + PL;
  fp16* klo = khi + PL;
  fp16* vtp = klo + PL;
  fp16* xh  = vtp + PL;
  fp16* xl  = xh + (size_t)M_*D_;
  const size_t need = (size_t)((char*)(xl + (size_t)M_*D_) - (char*)d_ws);

  hipLaunchKernelGGL(prep_w, dim3(3*768*768/256), dim3(256), 0, stream,
                     wq, wk, wv, wt);

  if (ws_size >= need) {
    for (int mat = 0; mat < 3; ++mat) {
      const float* x = mat == 0 ? xq : (mat == 1 ? xk : xv);
      hipLaunchKernelGGL(prep_x, dim3((M_*D_)/(256*8)), dim3(256), 0, stream,
                         x, xh, xl);
      hipLaunchKernelGGL(proj_gemmA, dim3(M_/64, H_), dim3(256), 0, stream,
                         xh, xl, wt + (size_t)mat*2*768*768,
                         mat == 1 ? khi : qhi, mat == 1 ? klo : qlo,
                         vtp, mat == 2 ? 1 : 0);
    }
  } else {
    hipLaunchKernelGGL(proj_gemm, dim3(M_/64, H_, 3), dim3(256), 0, stream,
                       xq, xk, xv, wt, qhi, qlo, khi, klo, vtp);
  }

  hipLaunchKernelGGL(mha_flash, dim3(S_/64, BH_), dim3(256), 0, stream,
                     qhi, qlo, khi, klo, vtp, out);
}

// Round 9
// 514.485 us; speedup vs baseline: 1.0611x; 1.0611x over previous
//
#include <hip/hip_runtime.h>
#include <cstdint>

// ---------- problem constants ----------
#define B_   2
#define S_   4096
#define D_   768
#define H_   12
#define DH_  64
#define BH_  (B_*H_)       // 24
#define M_   (B_*S_)       // 8192

typedef _Float16 fp16;
typedef __attribute__((ext_vector_type(8))) _Float16 fp16x8;
typedef __attribute__((ext_vector_type(4))) _Float16 fp16x4;
typedef __attribute__((ext_vector_type(4))) float    f32x4;

#define MFMA16(a,b,c) __builtin_amdgcn_mfma_f32_16x16x32_f16((a),(b),(c),0,0,0)

__device__ __forceinline__ float exp2_hw(float x) {
  float r; asm("v_exp_f32 %0, %1" : "=v"(r) : "v"(x)); return r;
}
__device__ __forceinline__ uint32_t pkrtz(float a, float b) {
  uint32_t r; asm("v_cvt_pkrtz_f16_f32 %0, %1, %2" : "=v"(r) : "v"(a), "v"(b));
  return r;
}

// ---------- async global->LDS, 16B ----------
__device__ __forceinline__ void gld_lds16(const void* g, void* l) {
  __builtin_amdgcn_global_load_lds(
      (const __attribute__((address_space(1))) unsigned int*)g,
      (__attribute__((address_space(3))) unsigned int*)l, 16, 0, 0);
}

// Stage a 64-row x 128-byte tile into LDS. Linear LDS dest (required by
// global_load_lds), inverse-swizzled GLOBAL source, swizzled reads.
__device__ __forceinline__ void stage64x128(const char* gbase, int pitch,
                                            char* lds, int tid) {
  const int lane = tid & 63, wv = tid >> 6;
#pragma unroll
  for (int j = 0; j < 2; ++j) {
    const int o   = (wv*2 + j)*1024 + lane*16;
    const int row = o >> 7;
    const int cb  = (o & 127) ^ ((row & 7) << 4);
    gld_lds16(gbase + (size_t)row*pitch + cb, lds + (wv*2 + j)*1024);
  }
}

// ---------- kernel 1: W transpose + hi/lo split ----------
__global__ __launch_bounds__(256) void prep_w(const float* __restrict__ wq,
                                              const float* __restrict__ wk,
                                              const float* __restrict__ wv,
                                              fp16* __restrict__ wt) {
  const int idx = blockIdx.x*256 + threadIdx.x;       // 3*768*768 total
  const int mat = idx / (768*768);
  const int e   = idx % (768*768);
  const int n   = e / 768, k = e % 768;
  const float* w = mat == 0 ? wq : (mat == 1 ? wk : wv);
  const float v = w[(size_t)k*768 + n];
  fp16* base = wt + (size_t)mat * (2*768*768);
  const fp16 hv = (fp16)v;
  base[e]            = hv;
  base[768*768 + e]  = (fp16)(v - (float)hv);
}

// ---------- kernel 2: projection GEMM (f16x3, inline split), 64x64 tile -----
__global__ __launch_bounds__(256) void proj_gemm(
    const float* __restrict__ xq, const float* __restrict__ xk,
    const float* __restrict__ xv, const fp16* __restrict__ wt,
    fp16* __restrict__ qhi, fp16* __restrict__ qlo,
    fp16* __restrict__ khi, fp16* __restrict__ klo,
    fp16* __restrict__ vtp) {
  __shared__ __align__(16) char sm[16384];
  char* sWh = sm;
  char* sWl = sm + 8192;
  const int tid = threadIdx.x, lane = tid & 63, wv = tid >> 6;
  const int c = lane & 15, g = lane >> 4;
  const int r128 = c * 128;
  const int co0 = ((c & 7) ^ g) << 4;
  const int co1 = co0 ^ 64;
  const int mb  = blockIdx.x * 64;
  const int h   = blockIdx.y;
  const int nb  = h * 64;
  const int mat = blockIdx.z;
  const float* x = mat == 0 ? xq : (mat == 1 ? xk : xv);
  const fp16* wth = wt + (size_t)mat * (2*768*768);
  const fp16* wtl = wth + 768*768;

  f32x4 acc[4] = {};
  const int xrow = mb + wv*16 + c;

  for (int k0 = 0; k0 < 768; k0 += 64) {
    __syncthreads();
    stage64x128((const char*)(wth + (size_t)nb*768 + k0), 1536, sWh, tid);
    stage64x128((const char*)(wtl + (size_t)nb*768 + k0), 1536, sWl, tid);
    __syncthreads();

    fp16x8 ah[2], al[2];
#pragma unroll
    for (int ks = 0; ks < 2; ++ks) {
      const float* xp = x + (size_t)xrow*768 + k0 + ks*32 + g*8;
      const f32x4 x0 = *(const f32x4*)xp;
      const f32x4 x1 = *(const f32x4*)(xp + 4);
#pragma unroll
      for (int j = 0; j < 8; ++j) {
        const float v = j < 4 ? x0[j] : x1[j - 4];
        const fp16 hv = (fp16)v;
        ah[ks][j] = hv;
        al[ks][j] = (fp16)(v - (float)hv);
      }
    }
#pragma unroll
    for (int ks = 0; ks < 2; ++ks)
#pragma unroll
      for (int nt = 0; nt < 4; ++nt) {
        const char* wb  = sWh + r128 + nt*2048;
        const char* wlb = sWl + r128 + nt*2048;
        const int co = ks ? co1 : co0;
        const fp16x8 bh = *(const fp16x8*)(wb  + co);
        const fp16x8 bl = *(const fp16x8*)(wlb + co);
        acc[nt] = MFMA16(ah[ks], bh, acc[nt]);
        acc[nt] = MFMA16(ah[ks], bl, acc[nt]);
        acc[nt] = MFMA16(al[ks], bh, acc[nt]);
      }
  }

  if (mat < 2) {
    fp16* ph = mat ? khi : qhi;
    fp16* pl = mat ? klo : qlo;
#pragma unroll
    for (int nt = 0; nt < 4; ++nt)
#pragma unroll
      for (int r = 0; r < 4; ++r) {
        const int m = mb + wv*16 + g*4 + r;      // C/D row = 4*(l>>4)+reg
        const int bb = m >> 12, s = m & (S_-1);
        const size_t idx = ((size_t)(bb*H_ + h)*S_ + s)*DH_ + nt*16 + c;
        const float v = acc[nt][r];
        const fp16 hv = (fp16)v;
        ph[idx] = hv;
        pl[idx] = (fp16)(v - (float)hv);
      }
  } else {
    // V: transpose 64x64 tile through LDS, store [d][s] coalesced
    __syncthreads();
    fp16* tile = (fp16*)sm;   // [64 d][64 m_local]
#pragma unroll
    for (int nt = 0; nt < 4; ++nt) {
      const int dd = nt*16 + c, ml = wv*16 + g*4;
      const fp16x4 hv = {(fp16)acc[nt][0], (fp16)acc[nt][1],
                         (fp16)acc[nt][2], (fp16)acc[nt][3]};
      *(fp16x4*)(tile + dd*64 + ml) = hv;
    }
    __syncthreads();
    const int bb = mb >> 12, s0 = mb & (S_-1);
    const int dd = tid >> 2, ml0 = (tid & 3) * 16;
    const size_t obase = ((size_t)(bb*H_ + h)*DH_ + dd)*S_ + s0 + ml0;
#pragma unroll
    for (int u = 0; u < 2; ++u)
      *(fp16x8*)(vtp + obase + u*8) = *(const fp16x8*)(tile + dd*64 + ml0 + u*8);
  }
}

// ---------- kernel 3: flash attention, 32-q strips ----------
// WG = one (b,h) x 128 q-rows; 4 waves x 32-q (2 subtiles of 16).
// Swapped QK^T: D[kv][q] = mfma(A=K_frag, B=Qt_frag) -> lane col = one q.
// K/V fragments shared across the 2 subtiles (halves LDS re-read per q-row).
// Row-sum of P via MFMA(P, ones) -> l kept in row layout (no shuffles).
// Defer-rescale: skip corr path when no new running max in the wave.
__global__ __launch_bounds__(256) void mha_flash(
    const fp16* __restrict__ qhi, const fp16* __restrict__ qlo,
    const fp16* __restrict__ khi, const fp16* __restrict__ klo,
    const fp16* __restrict__ vt, float* __restrict__ out) {
  __shared__ __align__(16) char sm[40960];
  char* sKh = sm;             // 8KB
  char* sKl = sm + 8192;      // 8KB
  char* sV  = sm + 16384;     // 8KB
  char* sP  = sm + 24576;     // 4 waves x 4KB

  const int tid = threadIdx.x, lane = tid & 63, wv = tid >> 6;
  const int c = lane & 15, g = lane >> 4;
  const int r128 = c * 128;
  const int co0 = ((c & 7) ^ g) << 4;      // == (g*16)^((c&7)<<4)
  const int co1 = co0 ^ 64;
  const int pg3 = (g & 1) << 3;
  const int pse = ((c & 7) ^ (g >> 1)) << 4;
  const int qb = blockIdx.x * 128;
  const int bh = blockIdx.y;
  const int b = bh / H_, h = bh % H_;

  // ---- prologue: Q 128 rows (hi+lo) through the whole 32KB LDS ----
  const size_t qoff = ((size_t)bh*S_ + qb) * DH_;
  stage64x128((const char*)(qhi + qoff),          128, sm,         tid);
  stage64x128((const char*)(qhi + qoff + 64*DH_), 128, sm +  8192, tid);
  stage64x128((const char*)(qlo + qoff),          128, sm + 16384, tid);
  stage64x128((const char*)(qlo + qoff + 64*DH_), 128, sm + 24576, tid);
  __syncthreads();

  fp16x8 qfh[2][2], qfl[2][2];
  {
    const char* hb = sm + (wv >> 1)*8192;           // Q rows (wv>>1)*64..
    const char* lb = sm + 16384 + (wv >> 1)*8192;
#pragma unroll
    for (int qs = 0; qs < 2; ++qs) {
      const int rl = ((wv & 1)*32 + qs*16 + c) * 128;   // row&7 == c&7
      qfh[qs][0] = *(const fp16x8*)(hb + rl + co0);
      qfh[qs][1] = *(const fp16x8*)(hb + rl + co1);
      qfl[qs][0] = *(const fp16x8*)(lb + rl + co0);
      qfl[qs][1] = *(const fp16x8*)(lb + rl + co1);
    }
  }

  float m_run[2] = {-1e30f, -1e30f};
  float lrow[2][4] = {};
  f32x4 accO[2][4] = {};
  fp16x8 ones;
#pragma unroll
  for (int j = 0; j < 8; ++j) ones[j] = (fp16)1.0f;
  const float C2 = 0.125f * 1.4426950408889634f;   // scale * log2(e)

  for (int kt = 0; kt < S_/64; ++kt) {
    __syncthreads();   // prior-iter LDS reads (Q-frag reads at kt=0) done
    const size_t koff = ((size_t)bh*S_ + kt*64) * DH_;
    stage64x128((const char*)(khi + koff), 128, sKh, tid);
    stage64x128((const char*)(klo + koff), 128, sKl, tid);
    stage64x128((const char*)(vt + (size_t)bh*DH_*S_ + kt*64), S_*2, sV, tid);
    __syncthreads();   // tiles resident

    // ---- QK^T (f16x3), K frags shared across both q-subtiles ----
    f32x4 accS[2][4] = {};
#pragma unroll
    for (int t = 0; t < 4; ++t) {
      const char* kb = sKh + r128 + t*2048;
      const char* lb = sKl + r128 + t*2048;
      const fp16x8 kh0 = *(const fp16x8*)(kb + co0);
      const fp16x8 kh1 = *(const fp16x8*)(kb + co1);
      const fp16x8 kl0 = *(const fp16x8*)(lb + co0);
      const fp16x8 kl1 = *(const fp16x8*)(lb + co1);
#pragma unroll
      for (int qs = 0; qs < 2; ++qs) {
        accS[qs][t] = MFMA16(kh0, qfh[qs][0], accS[qs][t]);
        accS[qs][t] = MFMA16(kh0, qfl[qs][0], accS[qs][t]);
        accS[qs][t] = MFMA16(kl0, qfh[qs][0], accS[qs][t]);
        accS[qs][t] = MFMA16(kh1, qfh[qs][1], accS[qs][t]);
        accS[qs][t] = MFMA16(kh1, qfl[qs][1], accS[qs][t]);
        accS[qs][t] = MFMA16(kl1, qfh[qs][1], accS[qs][t]);
      }
    }

    // ---- online softmax (lane owns q = subtile*16 + c) ----
    float mx0 = -1e30f, mx1 = -1e30f;
#pragma unroll
    for (int t = 0; t < 4; ++t) {
      mx0 = fmaxf(mx0, fmaxf(fmaxf(accS[0][t][0], accS[0][t][1]),
                             fmaxf(accS[0][t][2], accS[0][t][3])));
      mx1 = fmaxf(mx1, fmaxf(fmaxf(accS[1][t][0], accS[1][t][1]),
                             fmaxf(accS[1][t][2], accS[1][t][3])));
    }
    mx0 = fmaxf(mx0, __shfl_xor(mx0, 16));
    mx0 = fmaxf(mx0, __shfl_xor(mx0, 32));
    mx1 = fmaxf(mx1, __shfl_xor(mx1, 16));
    mx1 = fmaxf(mx1, __shfl_xor(mx1, 32));

    const bool rec = (mx0 > m_run[0]) || (mx1 > m_run[1]);
    if (__any(rec)) {
#pragma unroll
      for (int qs = 0; qs < 2; ++qs) {
        const float mxq = qs ? mx1 : mx0;
        const float m_new = fmaxf(m_run[qs], mxq);
        const float corr = exp2_hw(__builtin_fmaf(m_run[qs], C2, -m_new*C2));
        m_run[qs] = m_new;
        float crow[4];
#pragma unroll
        for (int r = 0; r < 4; ++r)
          crow[r] = __shfl(corr, (lane & 48) | (g*4 + r));
#pragma unroll
        for (int r = 0; r < 4; ++r) lrow[qs][r] *= crow[r];
#pragma unroll
        for (int d = 0; d < 4; ++d)
#pragma unroll
          for (int r = 0; r < 4; ++r) accO[qs][d][r] *= crow[r];
      }
    }

    // ---- P = exp2(fma(s,C2,-m*C2)) -> f16 strip in LDS (per wave, per qs) --
    char* pbase = sP + wv*4096 + r128;
#pragma unroll
    for (int qs = 0; qs < 2; ++qs) {
      const float negnm = -m_run[qs]*C2;
      char* pb = pbase + qs*2048;
#pragma unroll
      for (int t = 0; t < 4; ++t) {
        const float p0 = exp2_hw(__builtin_fmaf(accS[qs][t][0], C2, negnm));
        const float p1 = exp2_hw(__builtin_fmaf(accS[qs][t][1], C2, negnm));
        const float p2 = exp2_hw(__builtin_fmaf(accS[qs][t][2], C2, negnm));
        const float p3 = exp2_hw(__builtin_fmaf(accS[qs][t][3], C2, negnm));
        uint2 pw; pw.x = pkrtz(p0, p1); pw.y = pkrtz(p2, p3);
        *(uint2*)(pb + (pg3 | (pse ^ (t*32)))) = pw;
      }
    }

    // ---- P fragments back, row-sum via MFMA(ones), PV ----
    const fp16x8 pA0 = *(const fp16x8*)(pbase + co0);
    const fp16x8 pA1 = *(const fp16x8*)(pbase + co1);
    const fp16x8 pB0 = *(const fp16x8*)(pbase + 2048 + co0);
    const fp16x8 pB1 = *(const fp16x8*)(pbase + 2048 + co1);
    f32x4 aL0 = {}, aL1 = {};
    aL0 = MFMA16(pA0, ones, aL0);
    aL0 = MFMA16(pA1, ones, aL0);
    aL1 = MFMA16(pB0, ones, aL1);
    aL1 = MFMA16(pB1, ones, aL1);
#pragma unroll
    for (int d = 0; d < 4; ++d) {
      const char* vb = sV + r128 + d*2048;
      const fp16x8 v0 = *(const fp16x8*)(vb + co0);
      const fp16x8 v1 = *(const fp16x8*)(vb + co1);
      accO[0][d] = MFMA16(pA0, v0, accO[0][d]);
      accO[0][d] = MFMA16(pA1, v1, accO[0][d]);
      accO[1][d] = MFMA16(pB0, v0, accO[1][d]);
      accO[1][d] = MFMA16(pB1, v1, accO[1][d]);
    }
#pragma unroll
    for (int r = 0; r < 4; ++r) {
      lrow[0][r] += aL0[r];
      lrow[1][r] += aL1[r];
    }
  }

  // ---- epilogue: divide by l (already row layout), store ----
#pragma unroll
  for (int qs = 0; qs < 2; ++qs) {
    float inv[4];
#pragma unroll
    for (int r = 0; r < 4; ++r) inv[r] = 1.f / lrow[qs][r];
    const int s0 = qb + wv*32 + qs*16 + g*4;
#pragma unroll
    for (int d = 0; d < 4; ++d)
#pragma unroll
      for (int r = 0; r < 4; ++r)
        out[((size_t)(b*S_ + s0 + r))*D_ + h*DH_ + d*16 + c] =
            accO[qs][d][r] * inv[r];
  }
}

// ---------- launch ----------
extern "C" void kernel_launch(void* const* d_in, const int* in_sizes, int n_in,
                              void* d_out, int out_size, void* d_ws, size_t ws_size,
                              hipStream_t stream) {
  const float* xq = (const float*)d_in[0];
  const float* xk = (const float*)d_in[1];
  const float* xv = (const float*)d_in[2];
  const float* wq = (const float*)d_in[3];
  const float* wk = (const float*)d_in[4];
  const float* wv = (const float*)d_in[5];
  float* out = (float*)d_out;

  // ws layout (f16): Wt (6x768x768) | Qhi Qlo Khi Klo Vt   (~70 MB)
  fp16* wt  = (fp16*)d_ws;
  fp16* qhi = wt + (size_t)6*768*768;
  const size_t PL = (size_t)BH_*S_*DH_;
  fp16* qlo = qhi + PL;
  fp16* khi = qlo + PL;
  fp16* klo = khi + PL;
  fp16* vtp = klo + PL;

  hipLaunchKernelGGL(prep_w, dim3(3*768*768/256), dim3(256), 0, stream,
                     wq, wk, wv, wt);
  hipLaunchKernelGGL(proj_gemm, dim3(M_/64, H_, 3), dim3(256), 0, stream,
                     xq, xk, xv, wt, qhi, qlo, khi, klo, vtp);
  hipLaunchKernelGGL(mha_flash, dim3(S_/128, BH_), dim3(256), 0, stream,
                     qhi, qlo, khi, klo, vtp, out);
}